// Round 3
// baseline (620.491 us; speedup 1.0000x reference)
//
#include <hip/hip_runtime.h>

#define N_NODES 20000
#define N_EDGES 8192
#define DIM 128
#define NWORDS 313        // ceil(20000/64) node-words
#define XT_STRIDE 20032   // NWORDS*64, padded node dim for Xt
#define NT_STRIDE 20032   // maskNT row length in u64 (k1 writes all of it)
#define KSPLIT 4
#define WPC 80            // mask words per K-chunk in k2m (80,80,80,73)

typedef unsigned long long u64;
typedef __attribute__((ext_vector_type(8))) __bf16 bf16x8_t;
typedef __attribute__((ext_vector_type(4))) float f32x4;

__device__ __forceinline__ f32x4 mfma16(bf16x8_t a, bf16x8_t b, f32x4 c) {
  return __builtin_amdgcn_mfma_f32_16x16x32_bf16(a, b, c, 0, 0, 0);
}

// fp32 -> bf16 bits, round-to-nearest-even
__device__ __forceinline__ ushort f2bf(float f) {
  unsigned int x = __float_as_uint(f);
  unsigned int r = (x + 0x7FFFu + ((x >> 16) & 1u)) >> 16;
  return (ushort)r;
}

// expand 8 mask bits -> 8 bf16 values (1.0f / 0.0f), packed pairs
__device__ __forceinline__ bf16x8_t expand8(unsigned int byte) {
  union { unsigned int u[4]; bf16x8_t v; } A;
#pragma unroll
  for (int p = 0; p < 4; ++p) {
    unsigned int tt = (byte >> (2 * p)) & 3u;
    A.u[p] = ((tt | (tt << 15)) & 0x00010001u) * 0x3F80u;
  }
  return A.v;
}

#define GLOAD_LDS16(g, l)                                                  \
  __builtin_amdgcn_global_load_lds(                                        \
      (const __attribute__((address_space(1))) void*)(g),                  \
      (__attribute__((address_space(3))) void*)(l), 16, 0, 0)

// ---------------------------------------------------------------------------
// K0: Xt[d][n] = bf16(X[n][d]), n padded to XT_STRIDE with zeros.
// ---------------------------------------------------------------------------
__global__ __launch_bounds__(256) void k0_xt(const float* __restrict__ X,
                                             ushort* __restrict__ Xt) {
  __shared__ float T[64][129];
  const int t = threadIdx.x;
  const int n0 = blockIdx.x * 64;
#pragma unroll
  for (int i = 0; i < 32; ++i) {
    const int flat = i * 256 + t;
    const int nl = flat >> 7, d = flat & 127;
    const int n = n0 + nl;
    T[nl][d] = (n < N_NODES) ? X[(size_t)n * DIM + d] : 0.f;
  }
  __syncthreads();
  const int d = t >> 1, half = t & 1;
#pragma unroll
  for (int g = 0; g < 4; ++g) {
    union { ushort h[8]; int4 v; } u;
#pragma unroll
    for (int j = 0; j < 8; ++j) {
      const int nl = half * 32 + g * 8 + j;
      u.h[j] = f2bf(T[nl][d]);
    }
    *(int4*)&Xt[(size_t)d * XT_STRIDE + n0 + half * 32 + g * 8] = u.v;
  }
}

// ---------------------------------------------------------------------------
// K1: stream H once -> maskT[c][e] (bits = nodes), maskNT[ew][n] (bits = edges).
// No atomics, no LDS — pure streaming + ballots. grid (32, 313), block 256.
// Block y=312 writes bal=0 for n in [20000,20032) -> pad columns zeroed.
// ---------------------------------------------------------------------------
__global__ __launch_bounds__(256) void k1_mask(const float* __restrict__ H,
                                               u64* __restrict__ maskNT,
                                               u64* __restrict__ maskT) {
  const int tid  = threadIdx.x;
  const int wave = tid >> 6, lane = tid & 63;
  const int e  = blockIdx.x * 256 + wave * 64 + lane;
  const int n0 = blockIdx.y * 64;
  const int ew = blockIdx.x * 4 + wave;   // edge-window index 0..127

  u64 tmask = 0;
#pragma unroll 4
  for (int i = 0; i < 64; ++i) {
    const int n = n0 + i;
    const bool pred = (n < N_NODES) && (H[(size_t)n * N_EDGES + e] != 0.0f);
    const u64 bal = __ballot(pred);
    if (lane == 0) maskNT[(size_t)ew * NT_STRIDE + n] = bal;
    tmask |= pred ? (1ull << i) : 0ull;
  }
  maskT[(size_t)blockIdx.y * N_EDGES + e] = tmask;
}

// ---------------------------------------------------------------------------
// K_deg: De_inv[e] = 1/popcsum(maskT col e) (0 if 0);
//        Dv_inv[n] = 1/popcsum(maskNT col n). Deterministic, no atomics.
// ---------------------------------------------------------------------------
__global__ __launch_bounds__(256) void k_deg(const u64* __restrict__ maskT,
                                             const u64* __restrict__ maskNT,
                                             float* __restrict__ DeInv,
                                             float* __restrict__ DvInv) {
  const int t = blockIdx.x * 256 + threadIdx.x;
  if (t < N_EDGES) {
    int s = 0;
    for (int c = 0; c < NWORDS; ++c) s += __popcll(maskT[(size_t)c * N_EDGES + t]);
    DeInv[t] = s ? (1.0f / (float)s) : 0.0f;
  } else if (t < N_EDGES + N_NODES) {
    const int n = t - N_EDGES;
    int s = 0;
    for (int ew = 0; ew < 128; ++ew) s += __popcll(maskNT[(size_t)ew * NT_STRIDE + n]);
    DvInv[n] = s ? (1.0f / (float)s) : 0.0f;
  }
}

// ---------------------------------------------------------------------------
// K2m: Mp[p][e][d] partial of (H^T X). 256 blocks = 64 e-tiles x 4 K-chunks.
// 4 waves (2x2), wave tile 64x64, BK=64 (one mask word), MFMA 16x16x32 bf16.
// ---------------------------------------------------------------------------
__global__ __launch_bounds__(256) void k2m(const u64* __restrict__ maskT,
                                           const ushort* __restrict__ Xt,
                                           float* __restrict__ Mp) {
  __shared__ __align__(16) char lds[2][16384];
  const int t = threadIdx.x, lane = t & 63, w = t >> 6;
  const int wr = w >> 1, wc = w & 1;
  const int bid = blockIdx.x;
  const int p  = bid >> 6;
  const int eb = (bid & 63) * 128;
  const int w0 = p * WPC;
  const int nsteps = min(WPC, NWORDS - w0);
  const int l15 = lane & 15, lh = lane >> 4;

  f32x4 acc[4][4];
#pragma unroll
  for (int m = 0; m < 4; ++m)
#pragma unroll
    for (int n = 0; n < 4; ++n) acc[m][n] = (f32x4){0.f, 0.f, 0.f, 0.f};

  auto stage = [&](int buf, int ks) {
#pragma unroll
    for (int i = 0; i < 4; ++i) {
      const int flat = i * 256 + t;
      const int d = flat >> 3, sp = flat & 7;
      const int s = sp ^ (d & 7);                 // inverse-swizzled source
      const ushort* src = Xt + (size_t)d * XT_STRIDE + (w0 + ks) * 64 + s * 8;
      GLOAD_LDS16(src, &lds[buf][(i * 256 + w * 64) * 16]);
    }
  };
  auto loadwords = [&](u64* wd, int ks) {
#pragma unroll
    for (int m = 0; m < 4; ++m)
      wd[m] = maskT[(size_t)(w0 + ks) * N_EDGES + eb + wr * 64 + m * 16 + l15];
  };

  u64 wcur[4], wnxt[4];
  stage(0, 0);
  loadwords(wcur, 0);
  __syncthreads();

  int buf = 0;
  for (int ks = 0; ks < nsteps; ++ks) {
    const bool pre = (ks + 1 < nsteps);
    if (pre) { stage(buf ^ 1, ks + 1); loadwords(wnxt, ks + 1); }

    bf16x8_t bf[2][4];
#pragma unroll
    for (int kh = 0; kh < 2; ++kh)
#pragma unroll
      for (int fn = 0; fn < 4; ++fn) {
        const int c = wc * 64 + fn * 16 + l15;
        const int s = kh * 4 + lh;
        const int slot = 8 * c + (s ^ (c & 7));   // swizzled read
        bf[kh][fn] = *(const bf16x8_t*)&lds[buf][slot * 16];
      }
#pragma unroll
    for (int m = 0; m < 4; ++m) {
#pragma unroll
      for (int kh = 0; kh < 2; ++kh) {
        const unsigned int half = (unsigned int)(wcur[m] >> (kh * 32));
        const unsigned int byte = (half >> (lh * 8)) & 0xFFu;
        const bf16x8_t a = expand8(byte);
#pragma unroll
        for (int fn = 0; fn < 4; ++fn)
          acc[m][fn] = mfma16(a, bf[kh][fn], acc[m][fn]);
      }
    }
    __syncthreads();
    if (pre) {
#pragma unroll
      for (int m = 0; m < 4; ++m) wcur[m] = wnxt[m];
      buf ^= 1;
    }
  }

#pragma unroll
  for (int m = 0; m < 4; ++m)
#pragma unroll
    for (int fn = 0; fn < 4; ++fn)
#pragma unroll
      for (int r = 0; r < 4; ++r) {
        const int e = eb + wr * 64 + m * 16 + lh * 4 + r;
        const int d = wc * 64 + fn * 16 + l15;
        Mp[((size_t)p * N_EDGES + e) * DIM + d] = acc[m][fn][r];
      }
}

// ---------------------------------------------------------------------------
// K2r: Mt[d][e] = bf16( (sum_p Mp[p][e][d]) * De_inv[e] ).  256 blocks x 32 e.
// ---------------------------------------------------------------------------
__global__ __launch_bounds__(256) void k2r(const float* __restrict__ Mp,
                                           const float* __restrict__ DeInv,
                                           ushort* __restrict__ Mt) {
  __shared__ float T[32][129];
  const int t = threadIdx.x;
  const int eb = blockIdx.x * 32;
#pragma unroll
  for (int i = 0; i < 16; ++i) {
    const int flat = i * 256 + t;
    const int el = flat >> 7, d = flat & 127;
    const int e = eb + el;
    float s = 0.f;
#pragma unroll
    for (int p = 0; p < KSPLIT; ++p) s += Mp[((size_t)p * N_EDGES + e) * DIM + d];
    T[el][d] = s * DeInv[e];
  }
  __syncthreads();
#pragma unroll
  for (int i = 0; i < 16; ++i) {
    const int flat = i * 256 + t;
    const int el = flat & 31, d = flat >> 5;
    Mt[(size_t)d * N_EDGES + eb + el] = f2bf(T[el][d]);
  }
}

// ---------------------------------------------------------------------------
// K3m: Y[n][d] = Dv_inv[n] * (H M)[n][d]. 209 blocks, BM=96 (wave tile 48x64).
// ---------------------------------------------------------------------------
__global__ __launch_bounds__(256) void k3m(const u64* __restrict__ maskNT,
                                           const ushort* __restrict__ Mt,
                                           const float* __restrict__ DvInv,
                                           float* __restrict__ Y) {
  __shared__ __align__(16) char lds[2][16384];
  const int t = threadIdx.x, lane = t & 63, w = t >> 6;
  const int wr = w >> 1, wc = w & 1;
  const int nb = blockIdx.x * 96;
  const int l15 = lane & 15, lh = lane >> 4;

  f32x4 acc[3][4];
#pragma unroll
  for (int m = 0; m < 3; ++m)
#pragma unroll
    for (int n = 0; n < 4; ++n) acc[m][n] = (f32x4){0.f, 0.f, 0.f, 0.f};

  auto stage = [&](int buf, int ks) {
#pragma unroll
    for (int i = 0; i < 4; ++i) {
      const int flat = i * 256 + t;
      const int d = flat >> 3, sp = flat & 7;
      const int s = sp ^ (d & 7);
      const ushort* src = Mt + (size_t)d * N_EDGES + ks * 64 + s * 8;
      GLOAD_LDS16(src, &lds[buf][(i * 256 + w * 64) * 16]);
    }
  };
  auto loadwords = [&](u64* wd, int ks) {
#pragma unroll
    for (int m = 0; m < 3; ++m)
      wd[m] = maskNT[(size_t)ks * NT_STRIDE + nb + wr * 48 + m * 16 + l15];
  };

  u64 wcur[3], wnxt[3];
  stage(0, 0);
  loadwords(wcur, 0);
  __syncthreads();

  int buf = 0;
  for (int ks = 0; ks < 128; ++ks) {
    const bool pre = (ks + 1 < 128);
    if (pre) { stage(buf ^ 1, ks + 1); loadwords(wnxt, ks + 1); }

    bf16x8_t bf[2][4];
#pragma unroll
    for (int kh = 0; kh < 2; ++kh)
#pragma unroll
      for (int fn = 0; fn < 4; ++fn) {
        const int c = wc * 64 + fn * 16 + l15;
        const int s = kh * 4 + lh;
        const int slot = 8 * c + (s ^ (c & 7));
        bf[kh][fn] = *(const bf16x8_t*)&lds[buf][slot * 16];
      }
#pragma unroll
    for (int m = 0; m < 3; ++m) {
#pragma unroll
      for (int kh = 0; kh < 2; ++kh) {
        const unsigned int half = (unsigned int)(wcur[m] >> (kh * 32));
        const unsigned int byte = (half >> (lh * 8)) & 0xFFu;
        const bf16x8_t a = expand8(byte);
#pragma unroll
        for (int fn = 0; fn < 4; ++fn)
          acc[m][fn] = mfma16(a, bf[kh][fn], acc[m][fn]);
      }
    }
    __syncthreads();
    if (pre) {
#pragma unroll
      for (int m = 0; m < 3; ++m) wcur[m] = wnxt[m];
      buf ^= 1;
    }
  }

#pragma unroll
  for (int m = 0; m < 3; ++m)
#pragma unroll
    for (int fn = 0; fn < 4; ++fn)
#pragma unroll
      for (int r = 0; r < 4; ++r) {
        const int n = nb + wr * 48 + m * 16 + lh * 4 + r;
        if (n < N_NODES) {
          Y[(size_t)n * DIM + wc * 64 + fn * 16 + l15] = acc[m][fn][r] * DvInv[n];
        }
      }
}

// ---------------------------------------------------------------------------
// K4: out[n][o] = sum_d Y[n][d] * W[o][d] + b[o]  (in-place on d_out)
// ---------------------------------------------------------------------------
#define TILE_N 64
__global__ __launch_bounds__(256) void k4_out(const float* Y,
                                              const float* __restrict__ W,
                                              const float* __restrict__ b,
                                              float* out) {
  __shared__ float Wl[DIM][DIM + 1];   // Wl[d][o] = W[o][d]
  __shared__ float Yl[TILE_N][DIM];
  const int t  = threadIdx.x;
  const int n0 = blockIdx.x * TILE_N;

  {
    const int d = t & 127, oh = t >> 7;
    for (int k = 0; k < 64; ++k) {
      const int o = k * 2 + oh;
      Wl[d][o] = W[o * DIM + d];
    }
  }
  for (int r = 0; r < TILE_N * DIM / 256; ++r) {
    const int flat = r * 256 + t;
    const int nl = flat >> 7, d = flat & 127;
    const int n = n0 + nl;
    Yl[nl][d] = (n < N_NODES) ? Y[(size_t)n * DIM + d] : 0.f;
  }
  __syncthreads();

  const int o = t & 127;
  const float bias = b[o];
  for (int r = 0; r < TILE_N / 2; ++r) {
    const int nl = r * 2 + (t >> 7);
    const int n  = n0 + nl;
    float f = bias;
#pragma unroll 8
    for (int d = 0; d < DIM; ++d) f += Yl[nl][d] * Wl[d][o];
    if (n < N_NODES) out[(size_t)n * DIM + o] = f;
  }
}

// ---------------------------------------------------------------------------
extern "C" void kernel_launch(void* const* d_in, const int* in_sizes, int n_in,
                              void* d_out, int out_size, void* d_ws, size_t ws_size,
                              hipStream_t stream) {
  const float* X = (const float*)d_in[0];
  const float* H = (const float*)d_in[1];
  const float* W = (const float*)d_in[2];
  const float* b = (const float*)d_in[3];
  float* out = (float*)d_out;

  char* ws = (char*)d_ws;
  u64*    maskT  = (u64*)(ws + 0);            // 313*8192*8      = 20,512,768
  u64*    maskNT = (u64*)(ws + 20512768);     // 128*20032*8     = 20,512,768
  ushort* Xt     = (ushort*)(ws + 41025536);  // 128*20032*2     =  5,128,192
  float*  Mp     = (float*)(ws + 46153728);   // 4*8192*128*4    = 16,777,216
  ushort* Mt     = (ushort*)(ws + 62930944);  // 128*8192*2      =  2,097,152
  float*  DeInv  = (float*)(ws + 65028096);   // 32,768
  float*  DvInv  = (float*)(ws + 65060864);   // 80,000 (end ~65.1 MB)

  // no memsets: every buffer read downstream is fully written by a kernel first

  k0_xt  <<<313, 256, 0, stream>>>(X, Xt);
  k1_mask<<<dim3(32, 313), 256, 0, stream>>>(H, maskNT, maskT);
  k_deg  <<<(N_EDGES + N_NODES + 255) / 256, 256, 0, stream>>>(maskT, maskNT, DeInv, DvInv);
  k2m    <<<256, 256, 0, stream>>>(maskT, Xt, Mp);
  k2r    <<<256, 256, 0, stream>>>(Mp, DeInv, Mt);
  k3m    <<<209, 256, 0, stream>>>(maskNT, Mt, DvInv, out);
  k4_out <<<313, 256, 0, stream>>>(out, W, b, out);
}

// Round 4
// 427.864 us; speedup vs baseline: 1.4502x; 1.4502x over previous
//
#include <hip/hip_runtime.h>

#define N_NODES 20000
#define N_EDGES 8192
#define DIM 128
#define NWORDS 313        // ceil(20000/64) node-words
#define XT_STRIDE 20032   // NWORDS*64, padded node dim for Xt
#define NT_STRIDE 20032   // maskNT row length in u64 (k1 writes all of it)
#define KSPLIT 8
#define WPC 40            // mask words per K-chunk in k2m (7x40 + 33)
#define ZPAD 72           // Zl row stride (ushort): 144B = 9x16B, aligned + conflict-free

typedef unsigned long long u64;
typedef __attribute__((ext_vector_type(8))) __bf16 bf16x8_t;
typedef __attribute__((ext_vector_type(4))) float f32x4;

__device__ __forceinline__ f32x4 mfma16(bf16x8_t a, bf16x8_t b, f32x4 c) {
  return __builtin_amdgcn_mfma_f32_16x16x32_bf16(a, b, c, 0, 0, 0);
}

// fp32 -> bf16 bits, round-to-nearest-even
__device__ __forceinline__ ushort f2bf(float f) {
  unsigned int x = __float_as_uint(f);
  unsigned int r = (x + 0x7FFFu + ((x >> 16) & 1u)) >> 16;
  return (ushort)r;
}

// expand 8 mask bits -> 8 bf16 values (1.0/0.0); w = byte | byte<<15 once
__device__ __forceinline__ bf16x8_t expand8(unsigned int byte) {
  union { unsigned int u[4]; bf16x8_t v; } A;
  const unsigned int w = byte | (byte << 15);
#pragma unroll
  for (int p = 0; p < 4; ++p) {
    A.u[p] = ((w >> (2 * p)) & 0x00010001u) * 0x3F80u;
  }
  return A.v;
}

#define GLOAD_LDS16(g, l)                                                  \
  __builtin_amdgcn_global_load_lds(                                        \
      (const __attribute__((address_space(1))) void*)(g),                  \
      (__attribute__((address_space(3))) void*)(l), 16, 0, 0)

// ---------------------------------------------------------------------------
// K0: Xt[d][n] = bf16(X[n][d]), n padded to XT_STRIDE with zeros.
// ---------------------------------------------------------------------------
__global__ __launch_bounds__(256) void k0_xt(const float* __restrict__ X,
                                             ushort* __restrict__ Xt) {
  __shared__ float T[64][129];
  const int t = threadIdx.x;
  const int n0 = blockIdx.x * 64;
#pragma unroll
  for (int i = 0; i < 32; ++i) {
    const int flat = i * 256 + t;
    const int nl = flat >> 7, d = flat & 127;
    const int n = n0 + nl;
    T[nl][d] = (n < N_NODES) ? X[(size_t)n * DIM + d] : 0.f;
  }
  __syncthreads();
  const int d = t >> 1, half = t & 1;
#pragma unroll
  for (int g = 0; g < 4; ++g) {
    union { ushort h[8]; int4 v; } u;
#pragma unroll
    for (int j = 0; j < 8; ++j) {
      const int nl = half * 32 + g * 8 + j;
      u.h[j] = f2bf(T[nl][d]);
    }
    *(int4*)&Xt[(size_t)d * XT_STRIDE + n0 + half * 32 + g * 8] = u.v;
  }
}

// ---------------------------------------------------------------------------
// K1: stream H once -> maskT[c][e] (bits = nodes), maskNT[ew][n] (bits = edges).
// ---------------------------------------------------------------------------
__global__ __launch_bounds__(256) void k1_mask(const float* __restrict__ H,
                                               u64* __restrict__ maskNT,
                                               u64* __restrict__ maskT) {
  const int tid  = threadIdx.x;
  const int wave = tid >> 6, lane = tid & 63;
  const int e  = blockIdx.x * 256 + wave * 64 + lane;
  const int n0 = blockIdx.y * 64;
  const int ew = blockIdx.x * 4 + wave;   // edge-window index 0..127

  u64 tmask = 0;
#pragma unroll 8
  for (int i = 0; i < 64; ++i) {
    const int n = n0 + i;
    const bool pred = (n < N_NODES) && (H[(size_t)n * N_EDGES + e] != 0.0f);
    const u64 bal = __ballot(pred);
    if (lane == 0) maskNT[(size_t)ew * NT_STRIDE + n] = bal;
    tmask |= pred ? (1ull << i) : 0ull;
  }
  maskT[(size_t)blockIdx.y * N_EDGES + e] = tmask;
}

// ---------------------------------------------------------------------------
// K_deg: DeInv[e], DvInv[n] from mask popcounts. Deterministic, no atomics.
// ---------------------------------------------------------------------------
__global__ __launch_bounds__(256) void k_deg(const u64* __restrict__ maskT,
                                             const u64* __restrict__ maskNT,
                                             float* __restrict__ DeInv,
                                             float* __restrict__ DvInv) {
  const int t = blockIdx.x * 256 + threadIdx.x;
  if (t < N_EDGES) {
    int s = 0;
    for (int c = 0; c < NWORDS; ++c) s += __popcll(maskT[(size_t)c * N_EDGES + t]);
    DeInv[t] = s ? (1.0f / (float)s) : 0.0f;
  } else if (t < N_EDGES + N_NODES) {
    const int n = t - N_EDGES;
    int s = 0;
    for (int ew = 0; ew < 128; ++ew) s += __popcll(maskNT[(size_t)ew * NT_STRIDE + n]);
    DvInv[n] = s ? (1.0f / (float)s) : 0.0f;
  }
}

// ---------------------------------------------------------------------------
// K2m: Mp[p][e][d] partial of (H^T X). 512 blocks = 64 e-tiles x 8 K-chunks.
// 4 waves stacked on rows; wave tile 32x128 (m=2, fn=8) -> expansion amortized
// over 8 MFMA. 2 blocks/CU.
// ---------------------------------------------------------------------------
__global__ __launch_bounds__(256, 2) void k2m(const u64* __restrict__ maskT,
                                              const ushort* __restrict__ Xt,
                                              float* __restrict__ Mp) {
  __shared__ __align__(16) char lds[2][16384];
  const int t = threadIdx.x, lane = t & 63, w = t >> 6;
  const int bid = blockIdx.x;
  const int p  = bid >> 6;
  const int eb = (bid & 63) * 128;
  const int w0 = p * WPC;
  const int nsteps = min(WPC, NWORDS - w0);
  const int l15 = lane & 15, lh = lane >> 4;

  f32x4 acc[2][8];
#pragma unroll
  for (int m = 0; m < 2; ++m)
#pragma unroll
    for (int n = 0; n < 8; ++n) acc[m][n] = (f32x4){0.f, 0.f, 0.f, 0.f};

  auto stage = [&](int buf, int ks) {
#pragma unroll
    for (int i = 0; i < 4; ++i) {
      const int flat = i * 256 + t;
      const int d = flat >> 3, sp = flat & 7;
      const int s = sp ^ (d & 7);                 // inverse-swizzled source
      const ushort* src = Xt + (size_t)d * XT_STRIDE + (w0 + ks) * 64 + s * 8;
      GLOAD_LDS16(src, &lds[buf][(i * 256 + w * 64) * 16]);
    }
  };
  auto loadwords = [&](u64* wd, int ks) {
#pragma unroll
    for (int m = 0; m < 2; ++m)
      wd[m] = maskT[(size_t)(w0 + ks) * N_EDGES + eb + w * 32 + m * 16 + l15];
  };

  u64 wcur[2], wnxt[2];
  stage(0, 0);
  loadwords(wcur, 0);
  __syncthreads();

  int buf = 0;
  for (int ks = 0; ks < nsteps; ++ks) {
    const bool pre = (ks + 1 < nsteps);
    if (pre) { stage(buf ^ 1, ks + 1); loadwords(wnxt, ks + 1); }

    bf16x8_t bf[2][8];
#pragma unroll
    for (int kh = 0; kh < 2; ++kh)
#pragma unroll
      for (int fn = 0; fn < 8; ++fn) {
        const int c = fn * 16 + l15;
        const int s = kh * 4 + lh;
        const int slot = 8 * c + (s ^ (c & 7));   // swizzled read
        bf[kh][fn] = *(const bf16x8_t*)&lds[buf][slot * 16];
      }
#pragma unroll
    for (int m = 0; m < 2; ++m) {
#pragma unroll
      for (int kh = 0; kh < 2; ++kh) {
        const unsigned int half = (unsigned int)(wcur[m] >> (kh * 32));
        const unsigned int byte = (half >> (lh * 8)) & 0xFFu;
        const bf16x8_t a = expand8(byte);
#pragma unroll
        for (int fn = 0; fn < 8; ++fn)
          acc[m][fn] = mfma16(a, bf[kh][fn], acc[m][fn]);
      }
    }
    __syncthreads();
    if (pre) {
      wcur[0] = wnxt[0]; wcur[1] = wnxt[1];
      buf ^= 1;
    }
  }

#pragma unroll
  for (int m = 0; m < 2; ++m)
#pragma unroll
    for (int fn = 0; fn < 8; ++fn)
#pragma unroll
      for (int r = 0; r < 4; ++r) {
        const int e = eb + w * 32 + m * 16 + lh * 4 + r;
        const int d = fn * 16 + l15;
        Mp[((size_t)p * N_EDGES + e) * DIM + d] = acc[m][fn][r];
      }
}

// ---------------------------------------------------------------------------
// K2rz: M-row = (sum_p Mp) * DeInv  (bf16);  Z = M @ W^T  (MFMA);
//       Zt[o][e] = bf16(Z[e][o]) via LDS transpose. 128 blocks x 64 e.
// ---------------------------------------------------------------------------
__global__ __launch_bounds__(256) void k2rz(const float* __restrict__ Mp,
                                            const float* __restrict__ DeInv,
                                            const float* __restrict__ W,
                                            ushort* __restrict__ Zt) {
  __shared__ __align__(16) ushort Wb[16384];   // slot(o,sd)=o*16+(sd^(o&7)), 8 ushort each
  __shared__ __align__(16) ushort Mb[9216];    // union: A-tile (8192) / Zl[128][ZPAD]
  const int t = threadIdx.x, lane = t & 63, w = t >> 6;
  const int l15 = lane & 15, lh = lane >> 4;
  const int eb = blockIdx.x * 64;

  // stage W as bf16 B-operand (no transpose needed: B[k=d][col=o] = W[o][d])
#pragma unroll
  for (int i = 0; i < 8; ++i) {
    const int task = i * 256 + t;
    const int o = task >> 4, sd = task & 15;
    union { ushort h[8]; int4 v; } u;
    const float* src = W + o * DIM + sd * 8;
#pragma unroll
    for (int j = 0; j < 8; ++j) u.h[j] = f2bf(src[j]);
    *(int4*)&Wb[(o * 16 + (sd ^ (o & 7))) * 8] = u.v;
  }
  // reduce Mp partials + DeInv scale -> bf16 A-tile
#pragma unroll
  for (int i = 0; i < 4; ++i) {
    const int task = i * 256 + t;
    const int el = task >> 4, sd = task & 15;
    const int e = eb + el;
    float s[8] = {0.f, 0.f, 0.f, 0.f, 0.f, 0.f, 0.f, 0.f};
#pragma unroll
    for (int p = 0; p < KSPLIT; ++p) {
      const float* mp = Mp + ((size_t)p * N_EDGES + e) * DIM + sd * 8;
#pragma unroll
      for (int j = 0; j < 8; ++j) s[j] += mp[j];
    }
    const float sc = DeInv[e];
    union { ushort h[8]; int4 v; } u;
#pragma unroll
    for (int j = 0; j < 8; ++j) u.h[j] = f2bf(s[j] * sc);
    *(int4*)&Mb[(el * 16 + (sd ^ (el & 7))) * 8] = u.v;
  }
  __syncthreads();

  // GEMM: wave w -> e-rows w*16..+16, full 128 o. K=128 in 4 steps.
  f32x4 acc[8];
#pragma unroll
  for (int fn = 0; fn < 8; ++fn) acc[fn] = (f32x4){0.f, 0.f, 0.f, 0.f};
  const int el = w * 16 + l15;
#pragma unroll
  for (int ks = 0; ks < 4; ++ks) {
    const bf16x8_t a = *(const bf16x8_t*)&Mb[(el * 16 + ((ks * 4 + lh) ^ (el & 7))) * 8];
#pragma unroll
    for (int fn = 0; fn < 8; ++fn) {
      const int o = fn * 16 + l15;
      const bf16x8_t bfr = *(const bf16x8_t*)&Wb[(o * 16 + ((ks * 4 + lh) ^ (o & 7))) * 8];
      acc[fn] = mfma16(a, bfr, acc[fn]);
    }
  }
  __syncthreads();   // all waves done reading Mb A-tile

  // acc -> Zl[o][e_l] (transpose bounce)
#pragma unroll
  for (int fn = 0; fn < 8; ++fn) {
    const int o = fn * 16 + l15;
#pragma unroll
    for (int r = 0; r < 4; ++r) {
      const int elc = w * 16 + lh * 4 + r;
      Mb[o * ZPAD + elc] = f2bf(acc[fn][r]);
    }
  }
  __syncthreads();
  // coalesced global write: Zt[o][eb..eb+64)
#pragma unroll
  for (int i = 0; i < 4; ++i) {
    const int task = i * 256 + t;
    const int o = task >> 3, grp = task & 7;
    *(int4*)&Zt[(size_t)o * N_EDGES + eb + grp * 8] = *(const int4*)&Mb[o * ZPAD + grp * 8];
  }
}

// ---------------------------------------------------------------------------
// K3mf: out[n][o] = DvInv[n] * (H Z)[n][o] + b[o]. 313 blocks, BM=64
// (4 waves x 16 rows, fn=8). Writes final output directly.
// ---------------------------------------------------------------------------
__global__ __launch_bounds__(256, 2) void k3mf(const u64* __restrict__ maskNT,
                                               const ushort* __restrict__ Zt,
                                               const float* __restrict__ DvInv,
                                               const float* __restrict__ bias,
                                               float* __restrict__ out) {
  __shared__ __align__(16) char lds[2][16384];
  const int t = threadIdx.x, lane = t & 63, w = t >> 6;
  const int nb = blockIdx.x * 64;
  const int l15 = lane & 15, lh = lane >> 4;

  f32x4 acc[8];
#pragma unroll
  for (int fn = 0; fn < 8; ++fn) acc[fn] = (f32x4){0.f, 0.f, 0.f, 0.f};

  auto stage = [&](int buf, int ks) {
#pragma unroll
    for (int i = 0; i < 4; ++i) {
      const int flat = i * 256 + t;
      const int o = flat >> 3, sp = flat & 7;
      const int s = sp ^ (o & 7);
      const ushort* src = Zt + (size_t)o * N_EDGES + ks * 64 + s * 8;
      GLOAD_LDS16(src, &lds[buf][(i * 256 + w * 64) * 16]);
    }
  };

  u64 wcur, wnxt;
  stage(0, 0);
  wcur = maskNT[nb + w * 16 + l15];
  __syncthreads();

  int buf = 0;
  for (int ks = 0; ks < 128; ++ks) {
    const bool pre = (ks + 1 < 128);
    if (pre) {
      stage(buf ^ 1, ks + 1);
      wnxt = maskNT[(size_t)(ks + 1) * NT_STRIDE + nb + w * 16 + l15];
    }

    bf16x8_t bf[2][8];
#pragma unroll
    for (int kh = 0; kh < 2; ++kh)
#pragma unroll
      for (int fn = 0; fn < 8; ++fn) {
        const int c = fn * 16 + l15;
        const int s = kh * 4 + lh;
        const int slot = 8 * c + (s ^ (c & 7));
        bf[kh][fn] = *(const bf16x8_t*)&lds[buf][slot * 16];
      }
#pragma unroll
    for (int kh = 0; kh < 2; ++kh) {
      const unsigned int half = (unsigned int)(wcur >> (kh * 32));
      const unsigned int byte = (half >> (lh * 8)) & 0xFFu;
      const bf16x8_t a = expand8(byte);
#pragma unroll
      for (int fn = 0; fn < 8; ++fn)
        acc[fn] = mfma16(a, bf[kh][fn], acc[fn]);
    }
    __syncthreads();
    if (pre) { wcur = wnxt; buf ^= 1; }
  }

  float bv[8];
#pragma unroll
  for (int fn = 0; fn < 8; ++fn) bv[fn] = bias[fn * 16 + l15];
#pragma unroll
  for (int fn = 0; fn < 8; ++fn)
#pragma unroll
    for (int r = 0; r < 4; ++r) {
      const int n = nb + w * 16 + lh * 4 + r;
      if (n < N_NODES) {
        const int o = fn * 16 + l15;
        out[(size_t)n * DIM + o] = acc[fn][r] * DvInv[n] + bv[fn];
      }
    }
}

// ---------------------------------------------------------------------------
extern "C" void kernel_launch(void* const* d_in, const int* in_sizes, int n_in,
                              void* d_out, int out_size, void* d_ws, size_t ws_size,
                              hipStream_t stream) {
  const float* X = (const float*)d_in[0];
  const float* H = (const float*)d_in[1];
  const float* W = (const float*)d_in[2];
  const float* b = (const float*)d_in[3];
  float* out = (float*)d_out;

  char* ws = (char*)d_ws;
  u64*    maskT  = (u64*)(ws + 0);            // 313*8192*8    = 20,512,768
  u64*    maskNT = (u64*)(ws + 20512768);     // 128*20032*8   = 20,512,768
  ushort* Xt     = (ushort*)(ws + 41025536);  // 128*20032*2   =  5,128,192
  float*  Mp     = (float*)(ws + 46153728);   // 8*8192*128*4  = 33,554,432
  ushort* Zt     = (ushort*)(ws + 79708160);  // 128*8192*2    =  2,097,152
  float*  DeInv  = (float*)(ws + 81805312);   // 32,768
  float*  DvInv  = (float*)(ws + 81838080);   // 80,000 (end ~81.9 MB)

  k0_xt  <<<313, 256, 0, stream>>>(X, Xt);
  k1_mask<<<dim3(32, 313), 256, 0, stream>>>(H, maskNT, maskT);
  k_deg  <<<(N_EDGES + N_NODES + 255) / 256, 256, 0, stream>>>(maskT, maskNT, DeInv, DvInv);
  k2m    <<<512, 256, 0, stream>>>(maskT, Xt, Mp);
  k2rz   <<<128, 256, 0, stream>>>(Mp, DeInv, W, Zt);
  k3mf   <<<313, 256, 0, stream>>>(maskNT, Zt, DvInv, b, out);
}